// Round 7
// baseline (120.325 us; speedup 1.0000x reference)
//
#include <hip/hip_runtime.h>
#include <stdint.h>

// inputs [B=64, T=256, D=1024] f32; tanh -> sequential dual-threshold
// integrate-and-fire scan over T per (b,d).
//
// Structure = R5 (best, 109.6us) verbatim: intra-block T-pipeline.
// Block = 4 waves over the SAME seq group; wave k owns timesteps
// [64k,64k+64). v-state hops wave->wave via LDS acquire/release flag
// (intra-block only -> co-residency guaranteed, no deadlock).
//
// Round-7 single variable vs R5: each lane owns TWO adjacent d-sequences,
// all global ops are dwordx2 -> every memory instruction covers 512 B
// contiguous (vs 256 B) on BOTH streams. Theory: the kernel is pinned at
// ~2-3.5 TB/s effective by DRAM row-miss behavior of 256B-granule
// requests strided 4KB (fill kernel = whole-row streams = 6.3 TB/s).
// Block covers 128 seqs -> 512 blocks = 2 blocks/CU = 2 waves/SIMD
// (R5 proved 1->4 waves/SIMD worth <=1us, so TLP halving is cheap).
#define B_DIM 64
#define T_STEPS 256
#define D_DIM 1024
#define TPB 256
#define SEQ_PER_BLK 128         // 2 seqs per lane x 64 lanes
#define TQ 64                   // timesteps per wave (T/4)

typedef float f32x2 __attribute__((ext_vector_type(2)));

// XLA/Eigen f32 tanh rational approximation — bit-exact vs jnp.tanh
// (verified: absmax = 0.0). DO NOT change the FMA structure.
__device__ __forceinline__ float xla_tanhf(float x) {
    const float kClamp = 7.90531110763549805f;
    float xc = fminf(fmaxf(x, -kClamp), kClamp);
    float x2 = xc * xc;
    float p = __builtin_fmaf(x2, -2.76076847742355e-16f, 2.00018790482477e-13f);
    p = __builtin_fmaf(x2, p, -8.60467152213735e-11f);
    p = __builtin_fmaf(x2, p, 5.12229709037114e-08f);
    p = __builtin_fmaf(x2, p, 1.48572235717979e-05f);
    p = __builtin_fmaf(x2, p, 6.37261928875436e-04f);
    p = __builtin_fmaf(x2, p, 4.89352455891786e-03f);
    p = xc * p;
    float q = __builtin_fmaf(x2, 1.19825839466702e-06f, 1.18534705686654e-04f);
    q = __builtin_fmaf(x2, q, 2.26843463243900e-03f);
    q = __builtin_fmaf(x2, q, 4.89352518554385e-03f);
    float r = p / q;           // IEEE divide — required for bit-exactness
    return (fabsf(x) < 0.0004f) ? x : r;
}

// --- raw-asm building blocks ---------------------------------------------
// One dwordx2 load (two adjacent d of one timestep) + advance voff by one
// timestep (D_DIM*4 = 4096 B). saddr form: addr = SGPR base + zext(voff);
// tensor is 64 MB so 32-bit offsets fit. 8B-aligned (d even).
#define LD(i) "global_load_dwordx2 %" #i ", %16, %17\n\t" \
              "v_add_u32 %16, 0x1000, %16\n\t"

// Issue 16 loads into 16-pair slice B; compiler never sees them as memory
// ops -> no auto-waitcnt; vmcnt tracked manually.
#define ISSUE16(B) asm volatile( \
    LD(0) LD(1) LD(2) LD(3) LD(4) LD(5) LD(6) LD(7) \
    LD(8) LD(9) LD(10) LD(11) LD(12) LD(13) LD(14) LD(15) \
    : "=v"(B[0]), "=v"(B[1]), "=v"(B[2]), "=v"(B[3]), \
      "=v"(B[4]), "=v"(B[5]), "=v"(B[6]), "=v"(B[7]), \
      "=v"(B[8]), "=v"(B[9]), "=v"(B[10]), "=v"(B[11]), \
      "=v"(B[12]), "=v"(B[13]), "=v"(B[14]), "=v"(B[15]), \
      "+v"(voffi) \
    : "s"(inp_u) : "memory")

// Wait until <= CNT vmem ops outstanding; "+v" on the slice makes every
// use data-dependent on this wait. Only loads are in the queue during the
// tanh phase (all stores happen after), so vmcnt(0) at the tail is safe.
#define WAITBUF(B, CNT) asm volatile("s_waitcnt vmcnt(" CNT ")" \
    : "+v"(B[0]), "+v"(B[1]), "+v"(B[2]), "+v"(B[3]), \
      "+v"(B[4]), "+v"(B[5]), "+v"(B[6]), "+v"(B[7]), \
      "+v"(B[8]), "+v"(B[9]), "+v"(B[10]), "+v"(B[11]), \
      "+v"(B[12]), "+v"(B[13]), "+v"(B[14]), "+v"(B[15]) \
    :: "memory")

// Opaque keep-alive: pins the tanh results so the compiler cannot sink
// the tanh chains below the spin loop.
#define KEEP16(B) asm volatile("" \
    : "+v"(B[0]), "+v"(B[1]), "+v"(B[2]), "+v"(B[3]), \
      "+v"(B[4]), "+v"(B[5]), "+v"(B[6]), "+v"(B[7]), \
      "+v"(B[8]), "+v"(B[9]), "+v"(B[10]), "+v"(B[11]), \
      "+v"(B[12]), "+v"(B[13]), "+v"(B[14]), "+v"(B[15]))

#define TANH16(B) do { \
    _Pragma("unroll") \
    for (int u = 0; u < 16; ++u) { \
        B[u].x = xla_tanhf(B[u].x); \
        B[u].y = xla_tanhf(B[u].y); \
    } \
    KEEP16(B); } while (0)

// Scan 16 steps in place for BOTH sequences: consumes tanh value, leaves
// output. Bit-exact op order per sequence preserved (the *0.01 stays
// fused in the fma).
#define SCAN16(B) do { \
    _Pragma("unroll") \
    for (int u = 0; u < 16; ++u) { \
        float r0 = B[u].x; \
        v0 = __builtin_fmaf(r0, 0.01f, v0); \
        float sp0 = (v0 >= 1.0f)  ? 1.0f : 0.0f; \
        float sn0 = (v0 <= -1.0f) ? 1.0f : 0.0f; \
        v0 = (v0 - sp0) + sn0; \
        B[u].x = (sp0 - sn0) * 100.0f; \
        float r1 = B[u].y; \
        v1 = __builtin_fmaf(r1, 0.01f, v1); \
        float sp1 = (v1 >= 1.0f)  ? 1.0f : 0.0f; \
        float sn1 = (v1 <= -1.0f) ? 1.0f : 0.0f; \
        v1 = (v1 - sp1) + sn1; \
        B[u].y = (sp1 - sn1) * 100.0f; \
    } } while (0)

// 16 nontemporal dwordx2 stores (after handoff — nothing ever waits on
// vmcnt again, so retire latency is off the critical path; nt keeps the
// output stream from evicting the L3-resident input). voffo is a true
// "+v" in-out operand, advances 16 timesteps.
#define STORE16(B) asm volatile( \
    "global_store_dwordx2 %0, %1, %17 nt\n\t"  "v_add_u32 %0, 0x1000, %0\n\t" \
    "global_store_dwordx2 %0, %2, %17 nt\n\t"  "v_add_u32 %0, 0x1000, %0\n\t" \
    "global_store_dwordx2 %0, %3, %17 nt\n\t"  "v_add_u32 %0, 0x1000, %0\n\t" \
    "global_store_dwordx2 %0, %4, %17 nt\n\t"  "v_add_u32 %0, 0x1000, %0\n\t" \
    "global_store_dwordx2 %0, %5, %17 nt\n\t"  "v_add_u32 %0, 0x1000, %0\n\t" \
    "global_store_dwordx2 %0, %6, %17 nt\n\t"  "v_add_u32 %0, 0x1000, %0\n\t" \
    "global_store_dwordx2 %0, %7, %17 nt\n\t"  "v_add_u32 %0, 0x1000, %0\n\t" \
    "global_store_dwordx2 %0, %8, %17 nt\n\t"  "v_add_u32 %0, 0x1000, %0\n\t" \
    "global_store_dwordx2 %0, %9, %17 nt\n\t"  "v_add_u32 %0, 0x1000, %0\n\t" \
    "global_store_dwordx2 %0, %10, %17 nt\n\t" "v_add_u32 %0, 0x1000, %0\n\t" \
    "global_store_dwordx2 %0, %11, %17 nt\n\t" "v_add_u32 %0, 0x1000, %0\n\t" \
    "global_store_dwordx2 %0, %12, %17 nt\n\t" "v_add_u32 %0, 0x1000, %0\n\t" \
    "global_store_dwordx2 %0, %13, %17 nt\n\t" "v_add_u32 %0, 0x1000, %0\n\t" \
    "global_store_dwordx2 %0, %14, %17 nt\n\t" "v_add_u32 %0, 0x1000, %0\n\t" \
    "global_store_dwordx2 %0, %15, %17 nt\n\t" "v_add_u32 %0, 0x1000, %0\n\t" \
    "global_store_dwordx2 %0, %16, %17 nt\n\t" "v_add_u32 %0, 0x1000, %0\n\t" \
    : "+v"(voffo) \
    : "v"(B[0]), "v"(B[1]), "v"(B[2]), "v"(B[3]), \
      "v"(B[4]), "v"(B[5]), "v"(B[6]), "v"(B[7]), \
      "v"(B[8]), "v"(B[9]), "v"(B[10]), "v"(B[11]), \
      "v"(B[12]), "v"(B[13]), "v"(B[14]), "v"(B[15]), "s"(outp_u) \
    : "memory")

__global__ __launch_bounds__(TPB, 2)
void spike_scan_kernel(const float* __restrict__ in, float* __restrict__ out) {
    __shared__ float vstate[3][SEQ_PER_BLK];   // v handed stage k -> k+1
    __shared__ unsigned int flag[4];

    const int lane = threadIdx.x & 63;
    const int wk   = threadIdx.x >> 6;         // pipeline stage 0..3

    if (threadIdx.x < 4) flag[threadIdx.x] = 0u;
    __syncthreads();

    // Block handles 128 consecutive sequences (2 per lane); wave k handles
    // their timesteps [wk*64, wk*64+64). d = dbase + 2*lane (+0/+1).
    const uint32_t sgrp  = (uint32_t)blockIdx.x * SEQ_PER_BLK;
    const uint32_t b     = sgrp >> 10;               // batch index
    const uint32_t dbase = sgrp & (D_DIM - 1);       // d range base
    uint32_t voffi = b * (T_STEPS * D_DIM * 4u)
                   + (uint32_t)wk * (TQ * D_DIM * 4u)
                   + (dbase + 2u * (uint32_t)lane) * 4u;
    uint32_t voffo = voffi;
    const uint64_t inp_u  = (uint64_t)in;
    const uint64_t outp_u = (uint64_t)out;

    f32x2 rA[16], rB[16], rC[16], rD[16];      // this wave's 64 timesteps x2

    // Issue all 64 loads (cap-throttled past 63 outstanding — harmless),
    // then tanh each slice as it lands. All 4 waves do this in parallel.
    ISSUE16(rA); ISSUE16(rB); ISSUE16(rC); ISSUE16(rD);
    WAITBUF(rA, "48"); TANH16(rA);
    WAITBUF(rB, "32"); TANH16(rB);
    WAITBUF(rC, "16"); TANH16(rC);
    WAITBUF(rD, "0");  TANH16(rD);

    // --- serial section: only the 9-op v-chain per sequence ---
    float v0 = 0.0f, v1 = 0.0f;
    if (wk != 0) {
        while (__hip_atomic_load(&flag[wk - 1], __ATOMIC_ACQUIRE,
                                 __HIP_MEMORY_SCOPE_WORKGROUP) == 0u)
            __builtin_amdgcn_s_sleep(1);
        v0 = vstate[wk - 1][2 * lane];
        v1 = vstate[wk - 1][2 * lane + 1];
    }
    SCAN16(rA); SCAN16(rB); SCAN16(rC); SCAN16(rD);
    if (wk != 3) {
        vstate[wk][2 * lane]     = v0;
        vstate[wk][2 * lane + 1] = v1;
        __hip_atomic_store(&flag[wk], 1u, __ATOMIC_RELEASE,
                           __HIP_MEMORY_SCOPE_WORKGROUP);
    }
    // --- end serial section; stores off the critical chain ---

    STORE16(rA); STORE16(rB); STORE16(rC); STORE16(rD);
}

extern "C" void kernel_launch(void* const* d_in, const int* in_sizes, int n_in,
                              void* d_out, int out_size, void* d_ws, size_t ws_size,
                              hipStream_t stream) {
    const float* in = (const float*)d_in[0];
    float* out = (float*)d_out;
    dim3 block(TPB);
    dim3 grid((B_DIM * D_DIM) / SEQ_PER_BLK);   // 512 blocks = 2048 waves
    spike_scan_kernel<<<grid, block, 0, stream>>>(in, out);
}